// Round 5
// baseline (1705.151 us; speedup 1.0000x reference)
//
#include <hip/hip_runtime.h>
#include <stdint.h>

#define NDATA 200000
#define BATCH 256
#define BITD  64
#define TOPF  20
#define KNEG  2500
#define RANKA 20000            // N_DATA - HIGH
#define TVAL  7.2f
#define S8T   (8.0f/7.2f)
#define THRV  0.3f
#define TAU   0.976f
#define KHINV 42666.666f       // 1024/(1-TAU)

#define NB    512
#define HLO   (-0.35f)
#define HINV  1024.0f

#define NBLK  6250             // NDATA/32 mask words per sample
#define CFX   2048             // fnp candidate cap
#define CNX   6144             // neg candidate cap

#define WCH   8                // iterations of 128 rows per WG (chunk = 1024 rows)
#define NCH   196              // 196*1024 = 200704 >= 200000
#define NSB   8                // sample blocks of 32
#define BLKF  1024

typedef unsigned long long u64;
typedef __attribute__((ext_vector_type(16))) float f32x16;
typedef __attribute__((ext_vector_type(8))) short s16x8;

__device__ __forceinline__ int binOf(float sim) {
    int b = (int)floorf((sim - HLO) * HINV);
    b = b < 0 ? 0 : b;
    b = b > (NB - 1) ? (NB - 1) : b;
    return b;
}
__device__ __forceinline__ unsigned short bf16_rne(float x) {
    unsigned u = __float_as_uint(x);
    unsigned r = (u + 0x7FFFu + ((u >> 16) & 1u)) >> 16;
    return (unsigned short)r;
}

// ---------------------------------------------------------------- kernel A
__global__ __launch_bounds__(64) void k_prep(
    const float* __restrict__ iA, const float* __restrict__ iB,
    const float* __restrict__ tA, const float* __restrict__ tB,
    const float* __restrict__ mem, const int* __restrict__ bidx,
    unsigned short* __restrict__ fsumHi, unsigned short* __restrict__ fsumLo,
    float* __restrict__ fsumF, float* __restrict__ f1_g,
    float* __restrict__ upd_g, float* __restrict__ posExp_g,
    unsigned* __restrict__ hist_gp)
{
    int s = blockIdx.x, j = threadIdx.x;
    float a = iA[s * BITD + j], b = iB[s * BITD + j];
    float c = tA[s * BITD + j], d = tB[s * BITD + j];
    float f1 = 0.5f * (a + c), f2 = 0.5f * (a + d);
    float f3 = 0.5f * (b + c), f4 = 0.5f * (b + d);
    float q1 = f1 * f1, q2 = f2 * f2, q3 = f3 * f3, q4 = f4 * f4;
#pragma unroll
    for (int m = 1; m < 64; m <<= 1) {
        q1 += __shfl_xor(q1, m); q2 += __shfl_xor(q2, m);
        q3 += __shfl_xor(q3, m); q4 += __shfl_xor(q4, m);
    }
    float n1 = sqrtf(q1), n2 = sqrtf(q2), n3 = sqrtf(q3), n4 = sqrtf(q4);
    float fs = 0.25f * (f1 / n1 + f2 / n2 + f3 / n3 + f4 / n4);

    unsigned short hi = bf16_rne(fs);
    float hif = __uint_as_float(((unsigned)hi) << 16);
    unsigned short lo = bf16_rne(fs - hif);
    fsumHi[s * BITD + j] = hi;
    fsumLo[s * BITD + j] = lo;
    fsumF[s * BITD + j] = fs;
    f1_g[s * BITD + j] = f1;

    int pos = bidx[s];
    float mv = mem[(size_t)pos * BITD + j];
    float sg = (mv > 0.f) ? 1.f : ((mv < 0.f) ? -1.f : 0.f);
    float ps = sg * f1;
#pragma unroll
    for (int m = 1; m < 64; m <<= 1) ps += __shfl_xor(ps, m);

    float nf = f1 / n1;
    float u = mv * 0.4f + nf * 0.6f;
    float uq = u * u;
#pragma unroll
    for (int m = 1; m < 64; m <<= 1) uq += __shfl_xor(uq, m);
    upd_g[s * BITD + j] = u / sqrtf(uq);

    if (j == 0) posExp_g[s] = expf(ps / TVAL);
    for (int k = j; k < 256; k += 64) hist_gp[s * 256 + k] = 0u;
}

// ---------------------------------------------------------------- kernel P (pack mem -> bf16 B-fragments)
__global__ __launch_bounds__(256) void k_pack(const float* __restrict__ mem,
                                              unsigned short* __restrict__ memB)
{
    int t2 = blockIdx.x;
    int t = threadIdx.x;
    int sl = t & 31, h = (t >> 5) & 1, ks = t >> 6;
    const float* src = mem + (size_t)(t2 * 32 + sl) * BITD + ks * 16 + 8 * h;
    float4 v0 = *(const float4*)src;
    float4 v1 = *(const float4*)(src + 4);
    s16x8 o;
    o[0] = (short)bf16_rne(v0.x); o[1] = (short)bf16_rne(v0.y);
    o[2] = (short)bf16_rne(v0.z); o[3] = (short)bf16_rne(v0.w);
    o[4] = (short)bf16_rne(v1.x); o[5] = (short)bf16_rne(v1.y);
    o[6] = (short)bf16_rne(v1.z); o[7] = (short)bf16_rne(v1.w);
    *(s16x8*)(memB + ((size_t)(t2 * 4 + ks) * 2 + h) * 256 + sl * 8) = o;
}

// ---------------------------------------------------------------- kernel B (MFMA + histogram + LDS-buffered masks)
__global__ __launch_bounds__(256, 6) void k_main(
    const unsigned short* __restrict__ memB, const float* __restrict__ ru,
    const unsigned short* __restrict__ fsumHi, const unsigned short* __restrict__ fsumLo,
    unsigned* __restrict__ fnpMask, unsigned* __restrict__ negMask,
    unsigned* __restrict__ hist_gp)
{
    __shared__ unsigned histL[8 * NB];   // 16 KB: [smp>>2][bin], u8 lanes by smp&3
    __shared__ unsigned mFL[32 * 32];    // 4 KB:  [smp][blkLocal]
    __shared__ unsigned mNL[32 * 32];    // 4 KB

    const int tid = threadIdx.x;
    const int w = tid >> 6, l = tid & 63;
    const int h = l >> 5, sl = l & 31;
    const int sbBase = blockIdx.y * 32;
    const int chunkBase = blockIdx.x * 1024;

    for (int q = tid; q < 8 * NB; q += 256) histL[q] = 0u;
    for (int q = tid; q < 1024; q += 256) { mFL[q] = 0u; mNL[q] = 0u; }
    __syncthreads();

    // A fragments (fsum hi/lo): lane sl holds sample sbBase+sl, k-slice 8*h
    s16x8 aHi[4], aLo[4];
    {
        const unsigned short* ph = fsumHi + (size_t)(sbBase + sl) * BITD + 8 * h;
        const unsigned short* pl = fsumLo + (size_t)(sbBase + sl) * BITD + 8 * h;
#pragma unroll
        for (int ks = 0; ks < 4; ++ks) {
            aHi[ks] = *(const s16x8*)(ph + ks * 16);
            aLo[ks] = *(const s16x8*)(pl + ks * 16);
        }
    }
    const s16x8* bp = (const s16x8*)memB;

    s16x8 bcur[4], bnxt[4];
    {
        int waveRow = chunkBase + 32 * w;
        int t2 = (waveRow < NDATA) ? (waveRow >> 5) : 0;
#pragma unroll
        for (int ks = 0; ks < 4; ++ks)
            bcur[ks] = bp[((size_t)(t2 * 4 + ks) * 2 + h) * 32 + sl];
    }

    for (int it = 0; it < WCH; ++it) {
        const int waveRow = chunkBase + it * 128 + 32 * w;
        const bool valid = (waveRow < NDATA);

        float kk[16];
        if (valid) {
#pragma unroll
            for (int i = 0; i < 16; ++i) {
                int smp = (i & 3) + 8 * (i >> 2) + 4 * h;
                kk[i] = ru[(size_t)(sbBase + smp) * NDATA + waveRow + sl];
            }
        }
        {
            int nRow = chunkBase + (it + 1) * 128 + 32 * w;
            int t2 = (it + 1 < WCH && nRow < NDATA) ? (nRow >> 5) : 0;
#pragma unroll
            for (int ks = 0; ks < 4; ++ks)
                bnxt[ks] = bp[((size_t)(t2 * 4 + ks) * 2 + h) * 32 + sl];
        }

        if (valid) {
            f32x16 acc;
#pragma unroll
            for (int i = 0; i < 16; ++i) acc[i] = 0.f;
#pragma unroll
            for (int ks = 0; ks < 4; ++ks) {
                acc = __builtin_amdgcn_mfma_f32_32x32x16_bf16(aHi[ks], bcur[ks], acc, 0, 0, 0);
                acc = __builtin_amdgcn_mfma_f32_32x32x16_bf16(aLo[ks], bcur[ks], acc, 0, 0, 0);
            }

            const int blkLocal = it * 4 + w;
#pragma unroll
            for (int i = 0; i < 16; ++i) {
                float sim = acc[i];
                int smpL = (i & 3) + 8 * (i >> 2) + 4 * h;
                int bin = binOf(sim);
                atomicAdd(&histL[(smpL >> 2) * NB + bin], 1u << (8 * (i & 3)));
                u64 mF = __ballot(sim > THRV);
                u64 mN = __ballot(kk[i] > TAU);
                if ((l & 31) == 0) {
                    int smp = (i & 3) + 8 * (i >> 2) + (h << 2);
                    mFL[smp * 32 + blkLocal] = (unsigned)(mF >> (h << 5));
                    mNL[smp * 32 + blkLocal] = (unsigned)(mN >> (h << 5));
                }
            }
        }
#pragma unroll
        for (int ks = 0; ks < 4; ++ks) bcur[ks] = bnxt[ks];
    }

    __syncthreads();
    // coalesced mask writeout: lanes 0..31 write 128B contiguous per sample
    {
        const int blk0 = chunkBase >> 5;
        for (int q = tid; q < 1024; q += 256) {
            int smp = q >> 5, wd = q & 31;
            if (blk0 + wd < NBLK) {
                fnpMask[(size_t)(sbBase + smp) * NBLK + blk0 + wd] = mFL[q];
                negMask[(size_t)(sbBase + smp) * NBLK + blk0 + wd] = mNL[q];
            }
        }
    }
    // merge u8 histogram to global packed-u16 sample pairs
    for (int q = tid; q < 8 * NB; q += 256) {
        int g = q >> 9, bin = q & (NB - 1);
        unsigned wv = histL[g * NB + bin];
        if (!wv) continue;
        unsigned c0 = wv & 0xffu, c1 = (wv >> 8) & 0xffu;
        unsigned c2 = (wv >> 16) & 0xffu, c3 = wv >> 24;
        int sBase = sbBase + g * 4;          // even
        unsigned p01 = c0 | (c1 << 16), p23 = c2 | (c3 << 16);
        if (p01) atomicAdd(&hist_gp[(size_t)(sBase >> 1) * NB + bin], p01);
        if (p23) atomicAdd(&hist_gp[(size_t)((sBase >> 1) + 1) * NB + bin], p23);
    }
}

// ---------------------------------------------------------------- kernel C (per-sample finalize, 1024 threads)
__global__ __launch_bounds__(BLKF, 1) void k_fin(
    const int* __restrict__ bidx,
    const unsigned* __restrict__ fnpMask, const unsigned* __restrict__ negMask,
    const unsigned* __restrict__ hist_gp, const float* __restrict__ posExp_g,
    const float* __restrict__ f1_g, const float* __restrict__ fsumF,
    const float* __restrict__ mem, const float* __restrict__ ru,
    float* __restrict__ losses)
{
    __shared__ u64 arrF[CFX];                 // 16 KB
    __shared__ unsigned rowL[CNX];            // 24 KB (fnp rows, then neg rows)
    __shared__ unsigned negPk[CNX];           // 24 KB: kb<<18 | (0x3FFFF - row)
    __shared__ unsigned inclRow[KNEG + 64];   // 10 KB
    __shared__ unsigned khist[1024];          // 4 KB
    __shared__ unsigned scr[NB];              // 2 KB
    __shared__ float redF[BLKF];              // 4 KB
    __shared__ u64 wtop[16 * TOPF];           // 2.5 KB
    __shared__ u64 winPk[TOPF];
    __shared__ unsigned exclR[TOPF];
    __shared__ float numW[TOPF];
    __shared__ u64 bndV[64];
    __shared__ unsigned waveTot[16];
    __shared__ float f1sh[BITD], fssh[BITD];
    __shared__ int shI[4];
    __shared__ float shNum;
    __shared__ unsigned cFsh, cNsh, cPk, bndCnt;

    const int s = blockIdx.x, tid = threadIdx.x;
    const int w16 = tid >> 6, l = tid & 63;
    const int pos = bidx[s];

    if (tid == 0) { cFsh = 0u; cNsh = 0u; cPk = 0u; bndCnt = 0u; }
    if (tid < 16) ((float4*)f1sh)[tid] = ((const float4*)&f1_g[(size_t)s * BITD])[tid];
    else if (tid < 32) ((float4*)fssh)[tid - 16] = ((const float4*)&fsumF[(size_t)s * BITD])[tid - 16];
    if (tid < NB) {
        int sh = (s & 1) * 16;
        scr[tid] = (hist_gp[(size_t)(s >> 1) * NB + tid] >> sh) & 0xffffu;
    }
    for (int q = tid; q < 1024; q += BLKF) khist[q] = 0u;
    __syncthreads();

    // beta (thread 0) runs concurrently with the fnp mask scan (independent)
    if (tid == 0) {
        unsigned cum = 0; int beta = NB - 1;
        for (int b2 = 0; b2 < NB; ++b2) {
            cum += scr[b2];
            if (cum >= (unsigned)(RANKA + 1)) { beta = b2; break; }
        }
        shI[0] = beta;
    }
    // ---- fnp: compact rows
    for (int wi = tid; wi < NBLK; wi += BLKF) {
        unsigned w32 = fnpMask[(size_t)s * NBLK + wi];
        while (w32) {
            int b = __builtin_ctz(w32); w32 &= w32 - 1;
            unsigned slot = atomicAdd(&cFsh, 1u);
            if (slot < CFX) rowL[slot] = (unsigned)(wi * 32 + b);
        }
    }
    __syncthreads();
    unsigned cf = cFsh; if (cf > CFX) cf = CFX;

    // recompute exact f32 sims, build packed keys
    for (int i = tid; i < (int)cf; i += BLKF) {
        unsigned row = rowL[i];
        const float4* mr = (const float4*)&mem[(size_t)row * BITD];
        float sim = 0.f;
#pragma unroll
        for (int q = 0; q < 16; ++q) {
            float4 m4 = mr[q];
            sim += m4.x * fssh[q * 4] + m4.y * fssh[q * 4 + 1]
                 + m4.z * fssh[q * 4 + 2] + m4.w * fssh[q * 4 + 3];
        }
        arrF[i] = ((u64)__float_as_uint(sim) << 32) | (u64)(0x3FFFFu - row);
    }
    __syncthreads();

    // ---- per-wave top-20 (shfl only), then single-wave merge
    {
        int i1 = w16 * 64 + l, i2 = 1024 + w16 * 64 + l;
        u64 ta = (i1 < (int)cf) ? arrF[i1] : 0ull;
        u64 tb = (i2 < (int)cf) ? arrF[i2] : 0ull;
#pragma unroll
        for (int k = 0; k < TOPF; ++k) {
            u64 m = ta > tb ? ta : tb;
#pragma unroll
            for (int off = 1; off < 64; off <<= 1) { u64 o = __shfl_xor(m, off); if (o > m) m = o; }
            if (l == 0) wtop[w16 * TOPF + k] = m;
            if (ta == m) ta = 0ull; else if (tb == m) tb = 0ull;
        }
    }
    __syncthreads();
    if (w16 == 0) {
        u64 t[5];
#pragma unroll
        for (int j = 0; j < 5; ++j) t[j] = wtop[l * 5 + j];
#pragma unroll
        for (int k = 0; k < TOPF; ++k) {
            u64 m = t[0];
#pragma unroll
            for (int j = 1; j < 5; ++j) if (t[j] > m) m = t[j];
#pragma unroll
            for (int off = 1; off < 64; off <<= 1) { u64 o = __shfl_xor(m, off); if (o > m) m = o; }
            if (l == 0) winPk[k] = m;
#pragma unroll
            for (int j = 0; j < 5; ++j) if (t[j] == m) t[j] = 0ull;
        }
    }
    __syncthreads();
    if (tid == 0) {
        int ne = 0;
        for (int wi = 0; wi < TOPF; ++wi) {
            u64 pk = winPk[wi];
            if (pk == 0ull) break;
            unsigned row = 0x3FFFFu - (unsigned)(pk & 0x3FFFFull);
            float sim = __uint_as_float((unsigned)(pk >> 32));
            if ((int)row != pos && sim > THRV) exclR[ne++] = row;
        }
        shI[1] = ne;
    }
    __syncthreads();
    const int beta = shI[0], ne = shI[1];

    // e-dots for winners (4 lanes per entry)
    {
        int grp = tid >> 2, lp = tid & 3;
        if (grp < ne) {
            unsigned row = exclR[grp];
            const float* mr = mem + (size_t)row * BITD + lp * 16;
            const float* fr = &f1sh[lp * 16];
            float part = 0.f;
#pragma unroll
            for (int m2 = 0; m2 < 16; ++m2) part = fmaf(mr[m2], fr[m2], part);
            part += __shfl_xor(part, 1);
            part += __shfl_xor(part, 2);
            if (lp == 0) {
                float fsim = part * S8T;
                numW[grp] = fsim * expf(fsim);
            }
        }
    }
    __syncthreads();
    if (tid == 0) {
        float numer = posExp_g[s];
        for (int g = 0; g < ne; ++g) numer += numW[g];
        shNum = numer;
    }
    __syncthreads();

    // ---- neg: compact rows (reuse rowL)
    for (int wi = tid; wi < NBLK; wi += BLKF) {
        unsigned w32 = negMask[(size_t)s * NBLK + wi];
        while (w32) {
            int b = __builtin_ctz(w32); w32 &= w32 - 1;
            unsigned slot = atomicAdd(&cNsh, 1u);
            if (slot < CNX) rowL[slot] = (unsigned)(wi * 32 + b);
        }
    }
    __syncthreads();
    unsigned cn = cNsh; if (cn > CNX) cn = CNX;

    // process compacted rows: filter, recompute sim, key-bin, append
    for (int i = tid; i < (int)cn; i += BLKF) {
        unsigned row = rowL[i];
        if ((int)row == pos) continue;
        bool ex = false;
        for (int q2 = 0; q2 < ne; ++q2) ex = ex || (exclR[q2] == row);
        if (ex) continue;
        const float4* mr = (const float4*)&mem[(size_t)row * BITD];
        float sim = 0.f;
#pragma unroll
        for (int q = 0; q < 16; ++q) {
            float4 m4 = mr[q];
            sim += m4.x * fssh[q * 4] + m4.y * fssh[q * 4 + 1]
                 + m4.z * fssh[q * 4 + 2] + m4.w * fssh[q * 4 + 3];
        }
        if (binOf(sim) < beta) continue;
        float key = ru[(size_t)s * NDATA + row];
        int kb = (int)((key - TAU) * KHINV);
        kb = kb < 0 ? 0 : (kb > 1023 ? 1023 : kb);
        unsigned slot = atomicAdd(&cPk, 1u);
        if (slot < CNX) {
            negPk[slot] = ((unsigned)kb << 18) | (0x3FFFFu - row);
            atomicAdd(&khist[kb], 1u);
        }
    }
    __syncthreads();
    unsigned cp = cPk; if (cp > CNX) cp = CNX;

    if (tid == 0) {
        unsigned acc2 = 0; int Bs = 0;
        for (int b2 = 1023; b2 >= 0; --b2) {
            unsigned c2 = khist[b2];
            if (acc2 + c2 >= (unsigned)KNEG) { Bs = b2; break; }
            acc2 += c2;
            if (b2 == 0) Bs = 0;
        }
        shI[2] = Bs;
    }
    __syncthreads();
    const int Bstar = shI[2];

    // count strictly-above per thread, then shfl block scan
    unsigned cnt = 0;
    for (int i = tid; i < (int)cp; i += BLKF)
        if ((int)(negPk[i] >> 18) > Bstar) cnt++;
    unsigned pfx = cnt;
#pragma unroll
    for (int off = 1; off < 64; off <<= 1) {
        unsigned o = __shfl_up(pfx, off);
        if (l >= off) pfx += o;
    }
    if (l == 63) waveTot[w16] = pfx;
    __syncthreads();
    if (tid == 0) {
        unsigned run = 0;
        for (int q2 = 0; q2 < 16; ++q2) { unsigned t3 = waveTot[q2]; waveTot[q2] = run; run += t3; }
        shI[3] = (int)run;   // C1tot
    }
    __syncthreads();
    {
        unsigned off2 = waveTot[w16] + pfx - cnt;
        for (int i = tid; i < (int)cp; i += BLKF) {
            unsigned pk = negPk[i];
            int kb = (int)(pk >> 18);
            unsigned row = 0x3FFFFu - (pk & 0x3FFFFu);
            if (kb > Bstar) {
                inclRow[off2++] = row;
            } else if (kb == Bstar) {
                unsigned sl2 = atomicAdd(&bndCnt, 1u);
                if (sl2 < 64u) {
                    float key = ru[(size_t)s * NDATA + row];
                    bndV[sl2] = ((u64)__float_as_uint(key) << 32) | (u64)(0x3FFFFu - row);
                }
            }
        }
    }
    __syncthreads();
    if (tid == 0) {
        int C1 = shI[3];
        int m = KNEG - C1;
        int bc = (int)bndCnt; if (bc > 64) bc = 64;
        if (m > bc) m = bc;
        if (m < 0) m = 0;
        for (int t2 = 0; t2 < m; ++t2) {          // exact top-m of boundary bin
            u64 best = 0; int bi = -1;
            for (int q2 = 0; q2 < bc; ++q2)
                if (bndV[q2] > best) { best = bndV[q2]; bi = q2; }
            inclRow[C1 + t2] = 0x3FFFFu - (unsigned)(best & 0x3FFFFull);
            bndV[bi] = 0;
        }
        shI[3] = C1 + m;   // nInc
    }
    __syncthreads();
    const int nInc = shI[3];

    // denominator: e-dots over included rows
    float dsum = 0.f;
    for (int e2 = tid; e2 < nInc; e2 += BLKF) {
        unsigned row = inclRow[e2];
        const float4* mr = (const float4*)&mem[(size_t)row * BITD];
        float e = 0.f;
#pragma unroll
        for (int q = 0; q < 16; ++q) {
            float4 m4 = mr[q];
            e += m4.x * f1sh[q * 4] + m4.y * f1sh[q * 4 + 1]
               + m4.z * f1sh[q * 4 + 2] + m4.w * f1sh[q * 4 + 3];
        }
        dsum += expf(e * S8T);
    }
    redF[tid] = dsum;
    __syncthreads();
    for (int st = BLKF / 2; st > 0; st >>= 1) {
        if (tid < st) redF[tid] += redF[tid + st];
        __syncthreads();
    }
    if (tid == 0) {
        float D = redF[0] + posExp_g[s];
        losses[s] = -logf(shNum / D) / (1.0f + (float)ne);
    }
}

// ---------------------------------------------------------------- small kernels
__global__ __launch_bounds__(256) void k_loss(const float* __restrict__ losses,
                                              float* __restrict__ out)
{
    __shared__ float buf[256];
    int t = threadIdx.x;
    buf[t] = losses[t];
    __syncthreads();
    for (int st = 128; st > 0; st >>= 1) {
        if (t < st) buf[t] += buf[t + st];
        __syncthreads();
    }
    if (t == 0) out[0] = buf[0] / 256.0f;
}

__global__ __launch_bounds__(256) void k_copy(const float* __restrict__ mem,
                                              float* __restrict__ out)
{
    size_t i = ((size_t)blockIdx.x * 256 + threadIdx.x) * 4;
    if (i < (size_t)NDATA * BITD) {
        float4 v = *(const float4*)&mem[i];
        out[1 + i] = v.x; out[2 + i] = v.y; out[3 + i] = v.z; out[4 + i] = v.w;
    }
}

__global__ __launch_bounds__(64) void k_scatter(const int* __restrict__ bidx,
                                                const float* __restrict__ upd,
                                                float* __restrict__ out)
{
    int s = blockIdx.x, j = threadIdx.x;
    int pos = bidx[s];
    bool last = true;
    for (int s2 = s + 1; s2 < BATCH; ++s2)
        if (bidx[s2] == pos) last = false;   // last write wins (np semantics)
    if (last) out[1 + (size_t)pos * BITD + j] = upd[s * BITD + j];
}

// ---------------------------------------------------------------- launcher
extern "C" void kernel_launch(void* const* d_in, const int* in_sizes, int n_in,
                              void* d_out, int out_size, void* d_ws, size_t ws_size,
                              hipStream_t stream)
{
    const float* iA = (const float*)d_in[0];
    const float* iB = (const float*)d_in[1];
    const float* tA = (const float*)d_in[2];
    const float* tB = (const float*)d_in[3];
    const float* mem = (const float*)d_in[4];
    const float* ru  = (const float*)d_in[5];
    const int* bidx  = (const int*)d_in[6];
    float* out = (float*)d_out;

    char* w = (char*)d_ws;
    unsigned* fnpMask = (unsigned*)w;  w += (size_t)BATCH * NBLK * 4;     // 6.4 MB
    unsigned* negMask = (unsigned*)w;  w += (size_t)BATCH * NBLK * 4;     // 6.4 MB
    unsigned short* memB = (unsigned short*)w; w += (size_t)NDATA * BITD * 2;  // 25.6 MB
    unsigned* hist_gp = (unsigned*)w;  w += (size_t)(BATCH / 2) * NB * 4; // 256 KB
    float* fsumF = (float*)w;          w += BATCH * BITD * 4;
    float* f1_g = (float*)w;           w += BATCH * BITD * 4;
    float* upd_g = (float*)w;          w += BATCH * BITD * 4;
    float* posExp_g = (float*)w;       w += BATCH * 4;
    float* losses = (float*)w;         w += BATCH * 4;
    unsigned short* fsumHi = (unsigned short*)w; w += BATCH * BITD * 2;
    unsigned short* fsumLo = (unsigned short*)w; w += BATCH * BITD * 2;

    k_prep<<<BATCH, 64, 0, stream>>>(iA, iB, tA, tB, mem, bidx, fsumHi, fsumLo,
                                     fsumF, f1_g, upd_g, posExp_g, hist_gp);
    k_pack<<<NDATA / 32, 256, 0, stream>>>(mem, memB);
    k_copy<<<(NDATA * BITD) / 4 / 256, 256, 0, stream>>>(mem, out);
    k_main<<<dim3(NCH, NSB), 256, 0, stream>>>(memB, ru, fsumHi, fsumLo,
                                               fnpMask, negMask, hist_gp);
    k_fin<<<BATCH, BLKF, 0, stream>>>(bidx, fnpMask, negMask, hist_gp, posExp_g,
                                      f1_g, fsumF, mem, ru, losses);
    k_loss<<<1, 256, 0, stream>>>(losses, out);
    k_scatter<<<BATCH, 64, 0, stream>>>(bidx, upd_g, out);
}

// Round 6
// 355.188 us; speedup vs baseline: 4.8007x; 4.8007x over previous
//
#include <hip/hip_runtime.h>
#include <stdint.h>

#define NDATA 200000
#define BATCH 256
#define BITD  64
#define TOPF  20
#define KNEG  2500
#define RANKA 20000            // N_DATA - HIGH
#define TVAL  7.2f
#define S8T   (8.0f/7.2f)
#define THRV  0.3f
#define TAU   0.976f
#define KHINV 42666.666f       // 1024/(1-TAU)

#define NB    512
#define HLO   (-0.35f)
#define HINV  1024.0f

#define NBLK  6250             // NDATA/32 mask words per sample
#define CFX   2048             // fnp candidate cap
#define CNX   6144             // neg candidate cap

#define WCH   8                // iterations of 128 rows per WG (chunk = 1024 rows)
#define NCH   196              // 196*1024 = 200704 >= 200000
#define NSB   8                // sample blocks of 32
#define BLKF  1024

typedef unsigned long long u64;
typedef __attribute__((ext_vector_type(16))) float f32x16;
typedef __attribute__((ext_vector_type(8))) short s16x8;

__device__ __forceinline__ int binOf(float sim) {
    int b = (int)floorf((sim - HLO) * HINV);
    b = b < 0 ? 0 : b;
    b = b > (NB - 1) ? (NB - 1) : b;
    return b;
}
__device__ __forceinline__ unsigned short bf16_rne(float x) {
    unsigned u = __float_as_uint(x);
    unsigned r = (u + 0x7FFFu + ((u >> 16) & 1u)) >> 16;
    return (unsigned short)r;
}

// ---------------------------------------------------------------- kernel A
__global__ __launch_bounds__(64) void k_prep(
    const float* __restrict__ iA, const float* __restrict__ iB,
    const float* __restrict__ tA, const float* __restrict__ tB,
    const float* __restrict__ mem, const int* __restrict__ bidx,
    unsigned short* __restrict__ fsumHi, unsigned short* __restrict__ fsumLo,
    float* __restrict__ fsumF, float* __restrict__ f1_g,
    float* __restrict__ upd_g, float* __restrict__ posExp_g,
    unsigned* __restrict__ hist_gp)
{
    int s = blockIdx.x, j = threadIdx.x;
    float a = iA[s * BITD + j], b = iB[s * BITD + j];
    float c = tA[s * BITD + j], d = tB[s * BITD + j];
    float f1 = 0.5f * (a + c), f2 = 0.5f * (a + d);
    float f3 = 0.5f * (b + c), f4 = 0.5f * (b + d);
    float q1 = f1 * f1, q2 = f2 * f2, q3 = f3 * f3, q4 = f4 * f4;
#pragma unroll
    for (int m = 1; m < 64; m <<= 1) {
        q1 += __shfl_xor(q1, m); q2 += __shfl_xor(q2, m);
        q3 += __shfl_xor(q3, m); q4 += __shfl_xor(q4, m);
    }
    float n1 = sqrtf(q1), n2 = sqrtf(q2), n3 = sqrtf(q3), n4 = sqrtf(q4);
    float fs = 0.25f * (f1 / n1 + f2 / n2 + f3 / n3 + f4 / n4);

    unsigned short hi = bf16_rne(fs);
    float hif = __uint_as_float(((unsigned)hi) << 16);
    unsigned short lo = bf16_rne(fs - hif);
    fsumHi[s * BITD + j] = hi;
    fsumLo[s * BITD + j] = lo;
    fsumF[s * BITD + j] = fs;
    f1_g[s * BITD + j] = f1;

    int pos = bidx[s];
    float mv = mem[(size_t)pos * BITD + j];
    float sg = (mv > 0.f) ? 1.f : ((mv < 0.f) ? -1.f : 0.f);
    float ps = sg * f1;
#pragma unroll
    for (int m = 1; m < 64; m <<= 1) ps += __shfl_xor(ps, m);

    float nf = f1 / n1;
    float u = mv * 0.4f + nf * 0.6f;
    float uq = u * u;
#pragma unroll
    for (int m = 1; m < 64; m <<= 1) uq += __shfl_xor(uq, m);
    upd_g[s * BITD + j] = u / sqrtf(uq);

    if (j == 0) posExp_g[s] = expf(ps / TVAL);
    for (int k = j; k < 256; k += 64) hist_gp[s * 256 + k] = 0u;
}

// ---------------------------------------------------------------- kernel P (pack mem -> bf16 B-fragments)
__global__ __launch_bounds__(256) void k_pack(const float* __restrict__ mem,
                                              unsigned short* __restrict__ memB)
{
    int t2 = blockIdx.x;
    int t = threadIdx.x;
    int sl = t & 31, h = (t >> 5) & 1, ks = t >> 6;
    const float* src = mem + (size_t)(t2 * 32 + sl) * BITD + ks * 16 + 8 * h;
    float4 v0 = *(const float4*)src;
    float4 v1 = *(const float4*)(src + 4);
    s16x8 o;
    o[0] = (short)bf16_rne(v0.x); o[1] = (short)bf16_rne(v0.y);
    o[2] = (short)bf16_rne(v0.z); o[3] = (short)bf16_rne(v0.w);
    o[4] = (short)bf16_rne(v1.x); o[5] = (short)bf16_rne(v1.y);
    o[6] = (short)bf16_rne(v1.z); o[7] = (short)bf16_rne(v1.w);
    *(s16x8*)(memB + ((size_t)(t2 * 4 + ks) * 2 + h) * 256 + sl * 8) = o;
}

// ---------------------------------------------------------------- kernel B (MFMA + histogram + LDS-buffered masks)
__global__ __launch_bounds__(256, 4) void k_main(
    const unsigned short* __restrict__ memB, const float* __restrict__ ru,
    const unsigned short* __restrict__ fsumHi, const unsigned short* __restrict__ fsumLo,
    unsigned* __restrict__ fnpMask, unsigned* __restrict__ negMask,
    unsigned* __restrict__ hist_gp)
{
    __shared__ unsigned histL[8 * NB];   // 16 KB: [smp>>2][bin], u8 lanes by smp&3
    __shared__ unsigned mFL[32 * 32];    // 4 KB:  [smp][blkLocal]
    __shared__ unsigned mNL[32 * 32];    // 4 KB

    const int tid = threadIdx.x;
    const int w = tid >> 6, l = tid & 63;
    const int h = l >> 5, sl = l & 31;
    const int sbBase = blockIdx.y * 32;
    const int chunkBase = blockIdx.x * 1024;

    for (int q = tid; q < 8 * NB; q += 256) histL[q] = 0u;
    for (int q = tid; q < 1024; q += 256) { mFL[q] = 0u; mNL[q] = 0u; }
    __syncthreads();

    // A fragments (fsum hi/lo): lane sl holds sample sbBase+sl, k-slice 8*h
    s16x8 aHi[4], aLo[4];
    {
        const unsigned short* ph = fsumHi + (size_t)(sbBase + sl) * BITD + 8 * h;
        const unsigned short* pl = fsumLo + (size_t)(sbBase + sl) * BITD + 8 * h;
#pragma unroll
        for (int ks = 0; ks < 4; ++ks) {
            aHi[ks] = *(const s16x8*)(ph + ks * 16);
            aLo[ks] = *(const s16x8*)(pl + ks * 16);
        }
    }
    const s16x8* bp = (const s16x8*)memB;

    s16x8 bcur[4], bnxt[4];
    {
        int waveRow = chunkBase + 32 * w;
        int t2 = (waveRow < NDATA) ? (waveRow >> 5) : 0;
#pragma unroll
        for (int ks = 0; ks < 4; ++ks)
            bcur[ks] = bp[((size_t)(t2 * 4 + ks) * 2 + h) * 32 + sl];
    }

    for (int it = 0; it < WCH; ++it) {
        const int waveRow = chunkBase + it * 128 + 32 * w;
        const bool valid = (waveRow < NDATA);

        float kk[16];
        if (valid) {
#pragma unroll
            for (int i = 0; i < 16; ++i) {
                int smp = (i & 3) + 8 * (i >> 2) + 4 * h;
                kk[i] = ru[(size_t)(sbBase + smp) * NDATA + waveRow + sl];
            }
        }
        {
            int nRow = chunkBase + (it + 1) * 128 + 32 * w;
            int t2 = (it + 1 < WCH && nRow < NDATA) ? (nRow >> 5) : 0;
#pragma unroll
            for (int ks = 0; ks < 4; ++ks)
                bnxt[ks] = bp[((size_t)(t2 * 4 + ks) * 2 + h) * 32 + sl];
        }

        if (valid) {
            f32x16 acc;
#pragma unroll
            for (int i = 0; i < 16; ++i) acc[i] = 0.f;
#pragma unroll
            for (int ks = 0; ks < 4; ++ks) {
                acc = __builtin_amdgcn_mfma_f32_32x32x16_bf16(aHi[ks], bcur[ks], acc, 0, 0, 0);
                acc = __builtin_amdgcn_mfma_f32_32x32x16_bf16(aLo[ks], bcur[ks], acc, 0, 0, 0);
            }

            const int blkLocal = it * 4 + w;
#pragma unroll
            for (int i = 0; i < 16; ++i) {
                float sim = acc[i];
                int smpL = (i & 3) + 8 * (i >> 2) + 4 * h;
                int bin = binOf(sim);
                atomicAdd(&histL[(smpL >> 2) * NB + bin], 1u << (8 * (i & 3)));
                u64 mF = __ballot(sim > THRV);
                u64 mN = __ballot(kk[i] > TAU);
                if ((l & 31) == 0) {
                    int smp = (i & 3) + 8 * (i >> 2) + (h << 2);
                    mFL[smp * 32 + blkLocal] = (unsigned)(mF >> (h << 5));
                    mNL[smp * 32 + blkLocal] = (unsigned)(mN >> (h << 5));
                }
            }
        }
#pragma unroll
        for (int ks = 0; ks < 4; ++ks) bcur[ks] = bnxt[ks];
    }

    __syncthreads();
    // coalesced mask writeout: lanes 0..31 write 128B contiguous per sample
    {
        const int blk0 = chunkBase >> 5;
        for (int q = tid; q < 1024; q += 256) {
            int smp = q >> 5, wd = q & 31;
            if (blk0 + wd < NBLK) {
                fnpMask[(size_t)(sbBase + smp) * NBLK + blk0 + wd] = mFL[q];
                negMask[(size_t)(sbBase + smp) * NBLK + blk0 + wd] = mNL[q];
            }
        }
    }
    // merge u8 histogram to global packed-u16 sample pairs
    for (int q = tid; q < 8 * NB; q += 256) {
        int g = q >> 9, bin = q & (NB - 1);
        unsigned wv = histL[g * NB + bin];
        if (!wv) continue;
        unsigned c0 = wv & 0xffu, c1 = (wv >> 8) & 0xffu;
        unsigned c2 = (wv >> 16) & 0xffu, c3 = wv >> 24;
        int sBase = sbBase + g * 4;          // even
        unsigned p01 = c0 | (c1 << 16), p23 = c2 | (c3 << 16);
        if (p01) atomicAdd(&hist_gp[(size_t)(sBase >> 1) * NB + bin], p01);
        if (p23) atomicAdd(&hist_gp[(size_t)((sBase >> 1) + 1) * NB + bin], p23);
    }
}

// ---------------------------------------------------------------- kernel C (per-sample finalize, 1024 threads)
__global__ __launch_bounds__(BLKF, 1) void k_fin(
    const int* __restrict__ bidx,
    const unsigned* __restrict__ fnpMask, const unsigned* __restrict__ negMask,
    const unsigned* __restrict__ hist_gp, const float* __restrict__ posExp_g,
    const float* __restrict__ f1_g, const float* __restrict__ fsumF,
    const float* __restrict__ mem, const float* __restrict__ ru,
    float* __restrict__ losses)
{
    __shared__ u64 arrF[CFX];                 // 16 KB
    __shared__ unsigned rowL[CNX];            // 24 KB (fnp rows, then neg rows)
    __shared__ unsigned negPk[CNX];           // 24 KB: kb<<18 | (0x3FFFF - row)
    __shared__ unsigned inclRow[KNEG + 64];   // 10 KB
    __shared__ unsigned khist[1024];          // 4 KB
    __shared__ unsigned scr[NB];              // 2 KB
    __shared__ float redF[BLKF];              // 4 KB
    __shared__ u64 wtop[16 * TOPF];           // 2.5 KB
    __shared__ u64 winPk[TOPF];
    __shared__ unsigned exclR[TOPF];
    __shared__ float numW[TOPF];
    __shared__ u64 bndV[64];
    __shared__ unsigned waveTot[16];
    __shared__ float f1sh[BITD], fssh[BITD];
    __shared__ int shI[4];
    __shared__ float shNum;
    __shared__ unsigned cFsh, cNsh, cPk, bndCnt;

    const int s = blockIdx.x, tid = threadIdx.x;
    const int w16 = tid >> 6, l = tid & 63;
    const int pos = bidx[s];

    if (tid == 0) { cFsh = 0u; cNsh = 0u; cPk = 0u; bndCnt = 0u; }
    if (tid < 16) ((float4*)f1sh)[tid] = ((const float4*)&f1_g[(size_t)s * BITD])[tid];
    else if (tid < 32) ((float4*)fssh)[tid - 16] = ((const float4*)&fsumF[(size_t)s * BITD])[tid - 16];
    if (tid < NB) {
        int sh = (s & 1) * 16;
        scr[tid] = (hist_gp[(size_t)(s >> 1) * NB + tid] >> sh) & 0xffffu;
    }
    for (int q = tid; q < 1024; q += BLKF) khist[q] = 0u;
    __syncthreads();

    // beta (thread 0) runs concurrently with the fnp mask scan (independent)
    if (tid == 0) {
        unsigned cum = 0; int beta = NB - 1;
        for (int b2 = 0; b2 < NB; ++b2) {
            cum += scr[b2];
            if (cum >= (unsigned)(RANKA + 1)) { beta = b2; break; }
        }
        shI[0] = beta;
    }
    // ---- fnp: compact rows
    for (int wi = tid; wi < NBLK; wi += BLKF) {
        unsigned w32 = fnpMask[(size_t)s * NBLK + wi];
        while (w32) {
            int b = __builtin_ctz(w32); w32 &= w32 - 1;
            unsigned slot = atomicAdd(&cFsh, 1u);
            if (slot < CFX) rowL[slot] = (unsigned)(wi * 32 + b);
        }
    }
    __syncthreads();
    unsigned cf = cFsh; if (cf > CFX) cf = CFX;

    // recompute exact f32 sims, build packed keys
    for (int i = tid; i < (int)cf; i += BLKF) {
        unsigned row = rowL[i];
        const float4* mr = (const float4*)&mem[(size_t)row * BITD];
        float sim = 0.f;
#pragma unroll
        for (int q = 0; q < 16; ++q) {
            float4 m4 = mr[q];
            sim += m4.x * fssh[q * 4] + m4.y * fssh[q * 4 + 1]
                 + m4.z * fssh[q * 4 + 2] + m4.w * fssh[q * 4 + 3];
        }
        arrF[i] = ((u64)__float_as_uint(sim) << 32) | (u64)(0x3FFFFu - row);
    }
    __syncthreads();

    // ---- per-wave top-20 (shfl only), then single-wave merge
    {
        int i1 = w16 * 64 + l, i2 = 1024 + w16 * 64 + l;
        u64 ta = (i1 < (int)cf) ? arrF[i1] : 0ull;
        u64 tb = (i2 < (int)cf) ? arrF[i2] : 0ull;
#pragma unroll
        for (int k = 0; k < TOPF; ++k) {
            u64 m = ta > tb ? ta : tb;
#pragma unroll
            for (int off = 1; off < 64; off <<= 1) { u64 o = __shfl_xor(m, off); if (o > m) m = o; }
            if (l == 0) wtop[w16 * TOPF + k] = m;
            if (ta == m) ta = 0ull; else if (tb == m) tb = 0ull;
        }
    }
    __syncthreads();
    if (w16 == 0) {
        u64 t[5];
#pragma unroll
        for (int j = 0; j < 5; ++j) t[j] = wtop[l * 5 + j];
#pragma unroll
        for (int k = 0; k < TOPF; ++k) {
            u64 m = t[0];
#pragma unroll
            for (int j = 1; j < 5; ++j) if (t[j] > m) m = t[j];
#pragma unroll
            for (int off = 1; off < 64; off <<= 1) { u64 o = __shfl_xor(m, off); if (o > m) m = o; }
            if (l == 0) winPk[k] = m;
#pragma unroll
            for (int j = 0; j < 5; ++j) if (t[j] == m) t[j] = 0ull;
        }
    }
    __syncthreads();
    if (tid == 0) {
        int ne = 0;
        for (int wi = 0; wi < TOPF; ++wi) {
            u64 pk = winPk[wi];
            if (pk == 0ull) break;
            unsigned row = 0x3FFFFu - (unsigned)(pk & 0x3FFFFull);
            float sim = __uint_as_float((unsigned)(pk >> 32));
            if ((int)row != pos && sim > THRV) exclR[ne++] = row;
        }
        shI[1] = ne;
    }
    __syncthreads();
    const int beta = shI[0], ne = shI[1];

    // e-dots for winners (4 lanes per entry)
    {
        int grp = tid >> 2, lp = tid & 3;
        if (grp < ne) {
            unsigned row = exclR[grp];
            const float* mr = mem + (size_t)row * BITD + lp * 16;
            const float* fr = &f1sh[lp * 16];
            float part = 0.f;
#pragma unroll
            for (int m2 = 0; m2 < 16; ++m2) part = fmaf(mr[m2], fr[m2], part);
            part += __shfl_xor(part, 1);
            part += __shfl_xor(part, 2);
            if (lp == 0) {
                float fsim = part * S8T;
                numW[grp] = fsim * expf(fsim);
            }
        }
    }
    __syncthreads();
    if (tid == 0) {
        float numer = posExp_g[s];
        for (int g = 0; g < ne; ++g) numer += numW[g];
        shNum = numer;
    }
    __syncthreads();

    // ---- neg: compact rows (reuse rowL)
    for (int wi = tid; wi < NBLK; wi += BLKF) {
        unsigned w32 = negMask[(size_t)s * NBLK + wi];
        while (w32) {
            int b = __builtin_ctz(w32); w32 &= w32 - 1;
            unsigned slot = atomicAdd(&cNsh, 1u);
            if (slot < CNX) rowL[slot] = (unsigned)(wi * 32 + b);
        }
    }
    __syncthreads();
    unsigned cn = cNsh; if (cn > CNX) cn = CNX;

    // process compacted rows: filter, recompute sim, key-bin, append
    for (int i = tid; i < (int)cn; i += BLKF) {
        unsigned row = rowL[i];
        if ((int)row == pos) continue;
        bool ex = false;
        for (int q2 = 0; q2 < ne; ++q2) ex = ex || (exclR[q2] == row);
        if (ex) continue;
        const float4* mr = (const float4*)&mem[(size_t)row * BITD];
        float sim = 0.f;
#pragma unroll
        for (int q = 0; q < 16; ++q) {
            float4 m4 = mr[q];
            sim += m4.x * fssh[q * 4] + m4.y * fssh[q * 4 + 1]
                 + m4.z * fssh[q * 4 + 2] + m4.w * fssh[q * 4 + 3];
        }
        if (binOf(sim) < beta) continue;
        float key = ru[(size_t)s * NDATA + row];
        int kb = (int)((key - TAU) * KHINV);
        kb = kb < 0 ? 0 : (kb > 1023 ? 1023 : kb);
        unsigned slot = atomicAdd(&cPk, 1u);
        if (slot < CNX) {
            negPk[slot] = ((unsigned)kb << 18) | (0x3FFFFu - row);
            atomicAdd(&khist[kb], 1u);
        }
    }
    __syncthreads();
    unsigned cp = cPk; if (cp > CNX) cp = CNX;

    if (tid == 0) {
        unsigned acc2 = 0; int Bs = 0;
        for (int b2 = 1023; b2 >= 0; --b2) {
            unsigned c2 = khist[b2];
            if (acc2 + c2 >= (unsigned)KNEG) { Bs = b2; break; }
            acc2 += c2;
            if (b2 == 0) Bs = 0;
        }
        shI[2] = Bs;
    }
    __syncthreads();
    const int Bstar = shI[2];

    // count strictly-above per thread, then shfl block scan
    unsigned cnt = 0;
    for (int i = tid; i < (int)cp; i += BLKF)
        if ((int)(negPk[i] >> 18) > Bstar) cnt++;
    unsigned pfx = cnt;
#pragma unroll
    for (int off = 1; off < 64; off <<= 1) {
        unsigned o = __shfl_up(pfx, off);
        if (l >= off) pfx += o;
    }
    if (l == 63) waveTot[w16] = pfx;
    __syncthreads();
    if (tid == 0) {
        unsigned run = 0;
        for (int q2 = 0; q2 < 16; ++q2) { unsigned t3 = waveTot[q2]; waveTot[q2] = run; run += t3; }
        shI[3] = (int)run;   // C1tot
    }
    __syncthreads();
    {
        unsigned off2 = waveTot[w16] + pfx - cnt;
        for (int i = tid; i < (int)cp; i += BLKF) {
            unsigned pk = negPk[i];
            int kb = (int)(pk >> 18);
            unsigned row = 0x3FFFFu - (pk & 0x3FFFFu);
            if (kb > Bstar) {
                inclRow[off2++] = row;
            } else if (kb == Bstar) {
                unsigned sl2 = atomicAdd(&bndCnt, 1u);
                if (sl2 < 64u) {
                    float key = ru[(size_t)s * NDATA + row];
                    bndV[sl2] = ((u64)__float_as_uint(key) << 32) | (u64)(0x3FFFFu - row);
                }
            }
        }
    }
    __syncthreads();
    if (tid == 0) {
        int C1 = shI[3];
        int m = KNEG - C1;
        int bc = (int)bndCnt; if (bc > 64) bc = 64;
        if (m > bc) m = bc;
        if (m < 0) m = 0;
        for (int t2 = 0; t2 < m; ++t2) {          // exact top-m of boundary bin
            u64 best = 0; int bi = -1;
            for (int q2 = 0; q2 < bc; ++q2)
                if (bndV[q2] > best) { best = bndV[q2]; bi = q2; }
            inclRow[C1 + t2] = 0x3FFFFu - (unsigned)(best & 0x3FFFFull);
            bndV[bi] = 0;
        }
        shI[3] = C1 + m;   // nInc
    }
    __syncthreads();
    const int nInc = shI[3];

    // denominator: e-dots over included rows
    float dsum = 0.f;
    for (int e2 = tid; e2 < nInc; e2 += BLKF) {
        unsigned row = inclRow[e2];
        const float4* mr = (const float4*)&mem[(size_t)row * BITD];
        float e = 0.f;
#pragma unroll
        for (int q = 0; q < 16; ++q) {
            float4 m4 = mr[q];
            e += m4.x * f1sh[q * 4] + m4.y * f1sh[q * 4 + 1]
               + m4.z * f1sh[q * 4 + 2] + m4.w * f1sh[q * 4 + 3];
        }
        dsum += expf(e * S8T);
    }
    redF[tid] = dsum;
    __syncthreads();
    for (int st = BLKF / 2; st > 0; st >>= 1) {
        if (tid < st) redF[tid] += redF[tid + st];
        __syncthreads();
    }
    if (tid == 0) {
        float D = redF[0] + posExp_g[s];
        losses[s] = -logf(shNum / D) / (1.0f + (float)ne);
    }
}

// ---------------------------------------------------------------- small kernels
__global__ __launch_bounds__(256) void k_loss(const float* __restrict__ losses,
                                              float* __restrict__ out)
{
    __shared__ float buf[256];
    int t = threadIdx.x;
    buf[t] = losses[t];
    __syncthreads();
    for (int st = 128; st > 0; st >>= 1) {
        if (t < st) buf[t] += buf[t + st];
        __syncthreads();
    }
    if (t == 0) out[0] = buf[0] / 256.0f;
}

__global__ __launch_bounds__(256) void k_copy(const float* __restrict__ mem,
                                              float* __restrict__ out)
{
    size_t i = ((size_t)blockIdx.x * 256 + threadIdx.x) * 4;
    if (i < (size_t)NDATA * BITD) {
        float4 v = *(const float4*)&mem[i];
        out[1 + i] = v.x; out[2 + i] = v.y; out[3 + i] = v.z; out[4 + i] = v.w;
    }
}

__global__ __launch_bounds__(64) void k_scatter(const int* __restrict__ bidx,
                                                const float* __restrict__ upd,
                                                float* __restrict__ out)
{
    int s = blockIdx.x, j = threadIdx.x;
    int pos = bidx[s];
    bool last = true;
    for (int s2 = s + 1; s2 < BATCH; ++s2)
        if (bidx[s2] == pos) last = false;   // last write wins (np semantics)
    if (last) out[1 + (size_t)pos * BITD + j] = upd[s * BITD + j];
}

// ---------------------------------------------------------------- launcher
extern "C" void kernel_launch(void* const* d_in, const int* in_sizes, int n_in,
                              void* d_out, int out_size, void* d_ws, size_t ws_size,
                              hipStream_t stream)
{
    const float* iA = (const float*)d_in[0];
    const float* iB = (const float*)d_in[1];
    const float* tA = (const float*)d_in[2];
    const float* tB = (const float*)d_in[3];
    const float* mem = (const float*)d_in[4];
    const float* ru  = (const float*)d_in[5];
    const int* bidx  = (const int*)d_in[6];
    float* out = (float*)d_out;

    char* w = (char*)d_ws;
    unsigned* fnpMask = (unsigned*)w;  w += (size_t)BATCH * NBLK * 4;     // 6.4 MB
    unsigned* negMask = (unsigned*)w;  w += (size_t)BATCH * NBLK * 4;     // 6.4 MB
    unsigned short* memB = (unsigned short*)w; w += (size_t)NDATA * BITD * 2;  // 25.6 MB
    unsigned* hist_gp = (unsigned*)w;  w += (size_t)(BATCH / 2) * NB * 4; // 256 KB
    float* fsumF = (float*)w;          w += BATCH * BITD * 4;
    float* f1_g = (float*)w;           w += BATCH * BITD * 4;
    float* upd_g = (float*)w;          w += BATCH * BITD * 4;
    float* posExp_g = (float*)w;       w += BATCH * 4;
    float* losses = (float*)w;         w += BATCH * 4;
    unsigned short* fsumHi = (unsigned short*)w; w += BATCH * BITD * 2;
    unsigned short* fsumLo = (unsigned short*)w; w += BATCH * BITD * 2;

    k_prep<<<BATCH, 64, 0, stream>>>(iA, iB, tA, tB, mem, bidx, fsumHi, fsumLo,
                                     fsumF, f1_g, upd_g, posExp_g, hist_gp);
    k_pack<<<NDATA / 32, 256, 0, stream>>>(mem, memB);
    k_copy<<<(NDATA * BITD) / 4 / 256, 256, 0, stream>>>(mem, out);
    k_main<<<dim3(NCH, NSB), 256, 0, stream>>>(memB, ru, fsumHi, fsumLo,
                                               fnpMask, negMask, hist_gp);
    k_fin<<<BATCH, BLKF, 0, stream>>>(bidx, fnpMask, negMask, hist_gp, posExp_g,
                                      f1_g, fsumF, mem, ru, losses);
    k_loss<<<1, 256, 0, stream>>>(losses, out);
    k_scatter<<<BATCH, 64, 0, stream>>>(bidx, upd_g, out);
}